// Round 1
// baseline (745.428 us; speedup 1.0000x reference)
//
#include <hip/hip_runtime.h>

// CSAM: x:[32,64,192,192] f32, gamma:[1] f32
// energy[b,c,d] = <x[b,c,:], x[b,d,:]> over N=36864
// att = softmax(rowmax(energy) - energy, axis=-1)
// out = x + gamma * x * (att @ q)

#define BATCH 32
#define CH 64
#define NSP 36864          // 192*192
#define KCHUNK 512
#define KCHUNKS (NSP / KCHUNK)   // 72

// ---------------- Phase 1: Gram matrix (atomic accumulate over K-chunks) ----
__global__ __launch_bounds__(256) void gram_kernel(const float* __restrict__ x,
                                                   float* __restrict__ energy) {
    const int b = blockIdx.x;        // 0..31
    const int chunk = blockIdx.y;    // 0..71
    const int k0 = chunk * KCHUNK;

    __shared__ float tile[CH][65];   // +1 pad

    const int tid = threadIdx.x;
    const int tx = tid & 15;         // 0..15 -> d-block
    const int ty = tid >> 4;         // 0..15 -> c-block

    float acc[4][4];
#pragma unroll
    for (int i = 0; i < 4; i++)
#pragma unroll
        for (int j = 0; j < 4; j++) acc[i][j] = 0.f;

    const float* xb = x + (size_t)b * CH * NSP;

    for (int kk0 = 0; kk0 < KCHUNK; kk0 += 64) {
        __syncthreads();
#pragma unroll
        for (int i = 0; i < 16; i++) {
            int idx = i * 256 + tid;         // 0..4095
            int c = idx >> 6;
            int kk = idx & 63;
            tile[c][kk] = xb[(size_t)c * NSP + k0 + kk0 + kk];
        }
        __syncthreads();

#pragma unroll 4
        for (int kk = 0; kk < 64; kk++) {
            float a[4], bb[4];
#pragma unroll
            for (int i = 0; i < 4; i++) a[i] = tile[ty * 4 + i][kk];
#pragma unroll
            for (int j = 0; j < 4; j++) bb[j] = tile[tx * 4 + j][kk];
#pragma unroll
            for (int i = 0; i < 4; i++)
#pragma unroll
                for (int j = 0; j < 4; j++)
                    acc[i][j] = fmaf(a[i], bb[j], acc[i][j]);
        }
    }

    float* eb = energy + (size_t)b * CH * CH;
#pragma unroll
    for (int i = 0; i < 4; i++)
#pragma unroll
        for (int j = 0; j < 4; j++)
            atomicAdd(&eb[(ty * 4 + i) * CH + (tx * 4 + j)], acc[i][j]);
}

// ---------------- Phase 2: inverted softmax per row ------------------------
__global__ __launch_bounds__(64) void softmax_kernel(const float* __restrict__ energy,
                                                     float* __restrict__ att) {
    const int row = blockIdx.x;      // b*CH + c, 0..2047
    const int d = threadIdx.x;       // 0..63
    float e = energy[(size_t)row * CH + d];

    // row max of energy
    float m = e;
#pragma unroll
    for (int off = 32; off > 0; off >>= 1) m = fmaxf(m, __shfl_down(m, off));
    m = __shfl(m, 0);

    float en = m - e;                // energy_new

    // softmax over en
    float mx = en;
#pragma unroll
    for (int off = 32; off > 0; off >>= 1) mx = fmaxf(mx, __shfl_down(mx, off));
    mx = __shfl(mx, 0);

    float ex = __expf(en - mx);
    float s = ex;
#pragma unroll
    for (int off = 32; off > 0; off >>= 1) s += __shfl_down(s, off);
    s = __shfl(s, 0);

    att[(size_t)row * CH + d] = ex / s;
}

// ---------------- Phase 3: out = x + g*x*(att @ q) --------------------------
__global__ __launch_bounds__(256) void proj_kernel(const float* __restrict__ x,
                                                   const float* __restrict__ att,
                                                   const float* __restrict__ gamma,
                                                   float* __restrict__ out) {
    const int b = blockIdx.x;
    const int chunk = blockIdx.y;    // 0..71 -> 512 n each

    __shared__ float satt[CH][65];
    __shared__ float xt[CH][65];

    const int tid = threadIdx.x;
    const int tx = tid & 15;         // n-block
    const int ty = tid >> 4;         // c-block

    // stage attention[b] (64x64) into LDS
#pragma unroll
    for (int i = 0; i < 16; i++) {
        int idx = i * 256 + tid;
        satt[idx >> 6][idx & 63] = att[(size_t)b * CH * CH + idx];
    }

    const float g = gamma[0];
    const float* xb = x + (size_t)b * CH * NSP;
    float* ob = out + (size_t)b * CH * NSP;

    for (int nn0 = 0; nn0 < KCHUNK; nn0 += 64) {
        const int n0 = chunk * KCHUNK + nn0;
        __syncthreads();             // satt ready (1st iter) / prev compute done
#pragma unroll
        for (int i = 0; i < 16; i++) {
            int idx = i * 256 + tid;
            int c = idx >> 6;
            int kk = idx & 63;
            xt[c][kk] = xb[(size_t)c * NSP + n0 + kk];
        }
        __syncthreads();

        float acc[4][4] = {{0.f}};
#pragma unroll 4
        for (int d = 0; d < CH; d++) {
            float a[4], bb[4];
#pragma unroll
            for (int i = 0; i < 4; i++) a[i] = satt[ty * 4 + i][d];
#pragma unroll
            for (int j = 0; j < 4; j++) bb[j] = xt[d][tx * 4 + j];
#pragma unroll
            for (int i = 0; i < 4; i++)
#pragma unroll
                for (int j = 0; j < 4; j++)
                    acc[i][j] = fmaf(a[i], bb[j], acc[i][j]);
        }

        // fused epilogue: res = x + g*x*acc ; vectorized float4 store per c-row
#pragma unroll
        for (int i = 0; i < 4; i++) {
            int c = ty * 4 + i;
            float4 r;
            float xv0 = xt[c][tx * 4 + 0];
            float xv1 = xt[c][tx * 4 + 1];
            float xv2 = xt[c][tx * 4 + 2];
            float xv3 = xt[c][tx * 4 + 3];
            r.x = fmaf(g * xv0, acc[i][0], xv0);
            r.y = fmaf(g * xv1, acc[i][1], xv1);
            r.z = fmaf(g * xv2, acc[i][2], xv2);
            r.w = fmaf(g * xv3, acc[i][3], xv3);
            *(float4*)&ob[(size_t)c * NSP + n0 + tx * 4] = r;
        }
    }
}

extern "C" void kernel_launch(void* const* d_in, const int* in_sizes, int n_in,
                              void* d_out, int out_size, void* d_ws, size_t ws_size,
                              hipStream_t stream) {
    const float* x = (const float*)d_in[0];
    const float* gamma = (const float*)d_in[1];
    float* out = (float*)d_out;

    float* energy = (float*)d_ws;                    // 32*64*64 f32 = 512 KB
    float* att = energy + (size_t)BATCH * CH * CH;   // another 512 KB

    hipMemsetAsync(energy, 0, (size_t)BATCH * CH * CH * sizeof(float), stream);

    gram_kernel<<<dim3(BATCH, KCHUNKS), 256, 0, stream>>>(x, energy);
    softmax_kernel<<<BATCH * CH, 64, 0, stream>>>(energy, att);
    proj_kernel<<<dim3(BATCH, KCHUNKS), 256, 0, stream>>>(x, att, gamma, out);
}

// Round 2
// 597.745 us; speedup vs baseline: 1.2471x; 1.2471x over previous
//
#include <hip/hip_runtime.h>

// CSAM: x:[32,64,192,192] f32, gamma:[1] f32
// energy[b,c,d] = <x[b,c,:], x[b,d,:]>  (N=36864)
// att = softmax(rowmax(energy) - energy)
// out = x + gamma * x * (att @ q)
//
// Phase 1+3 use bf16 MFMA 16x16x32 (A/B: [m=lane&15][k=quad*8+j], C/D: col=lane&15, row=quad*4+reg)

#define BATCH 32
#define CH 64
#define NSP 36864

#define KSPLIT 36
#define KPER (NSP / KSPLIT)   // 1024
#define BK 64

#define NB 128                // proj n-chunk per block

using frag  = __attribute__((ext_vector_type(8))) short;   // 8 bf16 (4 VGPRs)
using f32x4 = __attribute__((ext_vector_type(4))) float;   // MFMA C/D

__device__ inline unsigned short f2bf(float f) {
    unsigned u = __builtin_bit_cast(unsigned, f);
    unsigned r = (u + 0x7FFFu + ((u >> 16) & 1u)) >> 16;   // RTNE
    return (unsigned short)r;
}
__device__ inline unsigned pack2(float a, float b) {
    return (unsigned)f2bf(a) | ((unsigned)f2bf(b) << 16);
}

// ---------------- Phase 1: Gram via MFMA, k-split + atomics -----------------
__global__ __launch_bounds__(256) void gram_kernel(const float* __restrict__ x,
                                                   float* __restrict__ energy) {
    const int b = blockIdx.x;
    const int kb = blockIdx.y;
    const int tid = threadIdx.x;
    const int wv = tid >> 6;
    const int lane = tid & 63;
    const int l15 = lane & 15;
    const int quad = lane >> 4;

    __shared__ unsigned short tile[CH][72];   // bf16, stride 144B (16B-mult, +pad)

    const float* xb = x + (size_t)b * CH * NSP + (size_t)kb * KPER;

    f32x4 acc[4];
#pragma unroll
    for (int cb = 0; cb < 4; cb++)
#pragma unroll
        for (int r = 0; r < 4; r++) acc[cb][r] = 0.f;

    for (int s = 0; s < KPER / BK; s++) {
        // global -> regs (64 rows x 64 k fp32, coalesced float4)
        float4 v[4];
#pragma unroll
        for (int rep = 0; rep < 4; rep++) {
            int idx = rep * 256 + tid;        // 0..1023 float4 slots, 16/row
            int c = idx >> 4, kq = idx & 15;
            v[rep] = *(const float4*)&xb[(size_t)c * NSP + s * BK + kq * 4];
        }
        __syncthreads();                      // prev iter's frag reads done
#pragma unroll
        for (int rep = 0; rep < 4; rep++) {
            int idx = rep * 256 + tid;
            int c = idx >> 4, kq = idx & 15;
            uint2 p;
            p.x = pack2(v[rep].x, v[rep].y);
            p.y = pack2(v[rep].z, v[rep].w);
            *(uint2*)&tile[c][kq * 4] = p;    // 8B aligned
        }
        __syncthreads();

#pragma unroll
        for (int ks = 0; ks < 2; ks++) {      // two K=32 steps
            frag a = *(const frag*)&tile[wv * 16 + l15][ks * 32 + quad * 8];
#pragma unroll
            for (int cb = 0; cb < 4; cb++) {
                frag bb = *(const frag*)&tile[cb * 16 + l15][ks * 32 + quad * 8];
                acc[cb] = __builtin_amdgcn_mfma_f32_16x16x32_bf16(a, bb, acc[cb], 0, 0, 0);
            }
        }
    }

    float* eb = energy + (size_t)b * CH * CH;
#pragma unroll
    for (int cb = 0; cb < 4; cb++)
#pragma unroll
        for (int r = 0; r < 4; r++) {
            int row = wv * 16 + quad * 4 + r;
            int col = cb * 16 + l15;
            atomicAdd(&eb[row * CH + col], acc[cb][r]);
        }
}

// ---------------- Phase 2: inverted softmax per row ------------------------
__global__ __launch_bounds__(64) void softmax_kernel(const float* __restrict__ energy,
                                                     float* __restrict__ att) {
    const int row = blockIdx.x;
    const int d = threadIdx.x;
    float e = energy[(size_t)row * CH + d];

    float m = e;
#pragma unroll
    for (int off = 32; off > 0; off >>= 1) m = fmaxf(m, __shfl_down(m, off));
    m = __shfl(m, 0);

    float en = m - e;

    float mx = en;
#pragma unroll
    for (int off = 32; off > 0; off >>= 1) mx = fmaxf(mx, __shfl_down(mx, off));
    mx = __shfl(mx, 0);

    float ex = __expf(en - mx);
    float s = ex;
#pragma unroll
    for (int off = 32; off > 0; off >>= 1) s += __shfl_down(s, off);
    s = __shfl(s, 0);

    att[(size_t)row * CH + d] = ex / s;
}

// ---------------- Phase 3: out = x + g*x*(att @ x) via MFMA -----------------
__global__ __launch_bounds__(256) void proj_kernel(const float* __restrict__ x,
                                                   const float* __restrict__ att,
                                                   const float* __restrict__ gamma,
                                                   float* __restrict__ out) {
    const int b = blockIdx.x;
    const int n0 = blockIdx.y * NB;
    const int tid = threadIdx.x;
    const int wv = tid >> 6;
    const int lane = tid & 63;
    const int l15 = lane & 15;
    const int quad = lane >> 4;

    __shared__ float xs[CH][NB + 1];            // fp32 x tile, 33KB (stride 129: bank-spread)
    __shared__ unsigned short satt[CH][72];     // bf16 att, 9.2KB

    const float* xb = x + (size_t)b * CH * NSP;

    // stage att[b] -> bf16 LDS
#pragma unroll
    for (int rep = 0; rep < 4; rep++) {
        int idx = rep * 256 + tid;              // 1024 float4 slots
        int c = idx >> 4, j = idx & 15;
        float4 v = *(const float4*)&att[(size_t)b * CH * CH + c * CH + j * 4];
        uint2 p;
        p.x = pack2(v.x, v.y);
        p.y = pack2(v.z, v.w);
        *(uint2*)&satt[c][j * 4] = p;
    }
    // stage x[b][:, n0:n0+NB] fp32 (coalesced float4 + b128 LDS writes)
#pragma unroll
    for (int rep = 0; rep < 8; rep++) {
        int idx = rep * 256 + tid;              // 2048 float4 slots, 32/row
        int d = idx >> 5, nq = idx & 31;
        float4 v = *(const float4*)&xb[(size_t)d * NSP + n0 + nq * 4];
        *(float4*)&xs[d][nq * 4] = v;
    }
    __syncthreads();

    const float g = gamma[0];

    // wave wv owns spatial tiles {2wv, 2wv+1} (16 n each), all 4 channel-blocks
    f32x4 acc[2][4];
#pragma unroll
    for (int t = 0; t < 2; t++)
#pragma unroll
        for (int cb = 0; cb < 4; cb++)
#pragma unroll
            for (int r = 0; r < 4; r++) acc[t][cb][r] = 0.f;

#pragma unroll
    for (int ks = 0; ks < 2; ks++) {            // K=64 -> two K=32 steps
        frag af[4];
#pragma unroll
        for (int cb = 0; cb < 4; cb++)
            af[cb] = *(const frag*)&satt[cb * 16 + l15][ks * 32 + quad * 8];
#pragma unroll
        for (int t = 0; t < 2; t++) {
            int n = (wv * 2 + t) * 16 + l15;
            // B frag: 8 fp32 gathered down a column of xs (stride 129 -> conflict-free)
            int k0 = ks * 32 + quad * 8;
            uint4 packed;
            packed.x = pack2(xs[k0 + 0][n], xs[k0 + 1][n]);
            packed.y = pack2(xs[k0 + 2][n], xs[k0 + 3][n]);
            packed.z = pack2(xs[k0 + 4][n], xs[k0 + 5][n]);
            packed.w = pack2(xs[k0 + 6][n], xs[k0 + 7][n]);
            frag bf = __builtin_bit_cast(frag, packed);
#pragma unroll
            for (int cb = 0; cb < 4; cb++)
                acc[t][cb] = __builtin_amdgcn_mfma_f32_16x16x32_bf16(af[cb], bf, acc[t][cb], 0, 0, 0);
        }
    }

    float* ob = out + (size_t)b * CH * NSP;
#pragma unroll
    for (int t = 0; t < 2; t++) {
        int n = (wv * 2 + t) * 16 + l15;
#pragma unroll
        for (int cb = 0; cb < 4; cb++)
#pragma unroll
            for (int r = 0; r < 4; r++) {
                int c = cb * 16 + quad * 4 + r;
                float xv = xs[c][n];
                ob[(size_t)c * NSP + n0 + n] = fmaf(xv * g, acc[t][cb][r], xv);
            }
    }
}

extern "C" void kernel_launch(void* const* d_in, const int* in_sizes, int n_in,
                              void* d_out, int out_size, void* d_ws, size_t ws_size,
                              hipStream_t stream) {
    const float* x = (const float*)d_in[0];
    const float* gamma = (const float*)d_in[1];
    float* out = (float*)d_out;

    float* energy = (float*)d_ws;                    // 32*64*64 f32 = 512 KB
    float* att = energy + (size_t)BATCH * CH * CH;   // +512 KB

    hipMemsetAsync(energy, 0, (size_t)BATCH * CH * CH * sizeof(float), stream);

    gram_kernel<<<dim3(BATCH, KSPLIT), 256, 0, stream>>>(x, energy);
    softmax_kernel<<<BATCH * CH, 64, 0, stream>>>(energy, att);
    proj_kernel<<<dim3(BATCH, NSP / NB), 256, 0, stream>>>(x, att, gamma, out);
}